// Round 1
// baseline (11383.236 us; speedup 1.0000x reference)
//
#include <hip/hip_runtime.h>
#include <hip/hip_bf16.h>
#include <stdint.h>

#define BB 32      // batch
#define SS 128     // memory length
#define TT 63      // time steps
#define UU 512     // units
#define EMBD 256
#define VV 32000
#define NW 256     // workgroups in persistent recurrence kernel
#define THR 256

typedef __attribute__((ext_vector_type(8))) short short8;
typedef __attribute__((ext_vector_type(4))) float f32x4;

static __device__ __forceinline__ unsigned short f2bf(float f) {
  union { float f; unsigned int u; } c; c.f = f;
  unsigned int u = c.u;
  unsigned int r = (u + 0x7FFFu + ((u >> 16) & 1u)) >> 16;  // RNE
  return (unsigned short)r;
}
static __device__ __forceinline__ float d4(float4 a, float4 b) {
  return a.x*b.x + a.y*b.y + a.z*b.z + a.w*b.w;
}
static __device__ __forceinline__ float sigm(float x) { return 1.f/(1.f + __expf(-x)); }
static __device__ __forceinline__ float tanh_(float x) { return 1.f - 2.f/(__expf(2.f*x) + 1.f); }

// ---------------------------------------------------------------- init
__global__ void init_kernel(unsigned int* flags, float* act, float* hnew0,
                            unsigned short* attnall, unsigned short* embg,
                            const float* enc) {
  int idx = blockIdx.x*blockDim.x + threadIdx.x;
  int stride = gridDim.x*blockDim.x;
  const int total = NW + BB*1024 + BB*UU + 32*UU + 32*EMBD;
  for (int i = idx; i < total; i += stride) {
    int j = i;
    if (j < NW) { flags[j] = 0u; continue; } j -= NW;
    if (j < BB*1024) { int b = j >> 10, c = j & 1023;
      act[j] = (c < UU) ? 0.f : enc[b*UU + (c - UU)]; continue; } j -= BB*1024;
    if (j < BB*UU) { hnew0[j] = enc[j]; continue; } j -= BB*UU;
    if (j < 32*UU) { attnall[2016*UU + j] = 0; continue; } j -= 32*UU;
    embg[2016*EMBD + j] = 0;
  }
}

// ---------------------------------------------------------------- elementwise converts
__global__ void conv_bf16(const float* __restrict__ in, unsigned short* __restrict__ out, int n) {
  int i = blockIdx.x*blockDim.x + threadIdx.x;
  if (i < n) out[i] = f2bf(in[i]);
}

__global__ void gather_emb(const int* __restrict__ x, const float* __restrict__ E,
                           unsigned short* __restrict__ embg) {
  int idx = blockIdx.x*blockDim.x + threadIdx.x;  // 2016*256 exact
  int m = idx >> 8, k = idx & 255;
  int t = m >> 5, b = m & 31;                     // m = t*32 + b
  int xi = x[b*TT + t];
  embg[m*EMBD + k] = f2bf(E[(size_t)xi*EMBD + k]);
}

// ---------------------------------------------------------------- transposes
__global__ void transpose_f32(const float* __restrict__ in, float* __restrict__ out, int R, int Cc) {
  __shared__ float tile[32][33];
  int bx = blockIdx.x*32, by = blockIdx.y*32;
  int tx = threadIdx.x & 31, ty = threadIdx.x >> 5;
  for (int i = 0; i < 4; ++i) {
    int r = by + ty + i*8;
    if (r < R && bx + tx < Cc) tile[ty + i*8][tx] = in[(size_t)r*Cc + bx + tx];
  }
  __syncthreads();
  for (int i = 0; i < 4; ++i) {
    int c = bx + ty + i*8;
    if (c < Cc && by + tx < R) out[(size_t)c*R + by + tx] = tile[tx][ty + i*8];
  }
}

__global__ void transpose_bf16(const float* __restrict__ in, unsigned short* __restrict__ out, int R, int Cc) {
  __shared__ float tile[32][33];
  int bx = blockIdx.x*32, by = blockIdx.y*32;
  int tx = threadIdx.x & 31, ty = threadIdx.x >> 5;
  for (int i = 0; i < 4; ++i) {
    int r = by + ty + i*8;
    if (r < R && bx + tx < Cc) tile[ty + i*8][tx] = in[(size_t)r*Cc + bx + tx];
  }
  __syncthreads();
  for (int i = 0; i < 4; ++i) {
    int c = bx + ty + i*8;
    if (c < Cc && by + tx < R) out[(size_t)c*R + by + tx] = f2bf(tile[tx][ty + i*8]);
  }
}

// ---------------------------------------------------------------- generic bf16 MFMA GEMM
// C[M,N] = A[M,K] @ Bt[N,K]^T (+bias). 128x128 tile, BK=32, 4 waves of 64x64.
__global__ __launch_bounds__(256) void gemm_bf16(
    const unsigned short* __restrict__ A, const unsigned short* __restrict__ Bt,
    const float* __restrict__ bias, float* __restrict__ C,
    int Mreal, int K, int N) {
  __shared__ __align__(16) unsigned short As[128*48];
  __shared__ __align__(16) unsigned short Bs[128*48];
  const int tid = threadIdx.x;
  const int m0 = blockIdx.y*128, n0 = blockIdx.x*128;
  const int wave = tid >> 6, lane = tid & 63;
  const int wm = (wave >> 1)*64, wn = (wave & 1)*64;
  const int fr = lane & 15, kq = (lane >> 4)*8, quad = lane >> 4;
  f32x4 acc[4][4];
#pragma unroll
  for (int mt = 0; mt < 4; ++mt)
#pragma unroll
    for (int nt = 0; nt < 4; ++nt) acc[mt][nt] = (f32x4){0.f, 0.f, 0.f, 0.f};
  const int nkt = K >> 5;
  for (int kt = 0; kt < nkt; ++kt) {
    __syncthreads();
#pragma unroll
    for (int i = 0; i < 2; ++i) {
      int g = tid + i*256;
      int r = g >> 2, seg = g & 3;
      *(uint4*)&As[r*48 + seg*8] = *(const uint4*)&A[(size_t)(m0 + r)*K + kt*32 + seg*8];
      *(uint4*)&Bs[r*48 + seg*8] = *(const uint4*)&Bt[(size_t)(n0 + r)*K + kt*32 + seg*8];
    }
    __syncthreads();
    short8 af[4], bf[4];
#pragma unroll
    for (int mt = 0; mt < 4; ++mt) af[mt] = *(const short8*)&As[(wm + mt*16 + fr)*48 + kq];
#pragma unroll
    for (int nt = 0; nt < 4; ++nt) bf[nt] = *(const short8*)&Bs[(wn + nt*16 + fr)*48 + kq];
#pragma unroll
    for (int mt = 0; mt < 4; ++mt)
#pragma unroll
      for (int nt = 0; nt < 4; ++nt)
        acc[mt][nt] = __builtin_amdgcn_mfma_f32_16x16x32_bf16(af[mt], bf[nt], acc[mt][nt], 0, 0, 0);
  }
  // C/D layout: col = lane&15, row = quad*4 + reg  [m89-verified]
#pragma unroll
  for (int mt = 0; mt < 4; ++mt) {
    int mb = m0 + wm + mt*16 + quad*4;
#pragma unroll
    for (int nt = 0; nt < 4; ++nt) {
      int ng = n0 + wn + nt*16 + fr;
      float bv = bias ? bias[ng] : 0.f;
#pragma unroll
      for (int reg = 0; reg < 4; ++reg) {
        int mg = mb + reg;
        if (mg < Mreal) C[(size_t)mg*N + ng] = acc[mt][nt][reg] + bv;
      }
    }
  }
}

// ---------------------------------------------------------------- grid barrier (own flags; all-read-all)
static __device__ __forceinline__ void gbar(unsigned int* flags, unsigned int ep, int tid, int bid) {
  __syncthreads();
  __threadfence();  // release my writes device-wide
  if (tid == 0)
    __hip_atomic_store(&flags[bid], ep, __ATOMIC_RELAXED, __HIP_MEMORY_SCOPE_AGENT);
  // 256 threads poll one flag each (NW == THR)
  while (__hip_atomic_load(&flags[tid], __ATOMIC_RELAXED, __HIP_MEMORY_SCOPE_AGENT) < ep) {
    __builtin_amdgcn_s_sleep(1);
  }
  __threadfence();  // acquire others' writes
  __syncthreads();
}

// ---------------------------------------------------------------- persistent recurrence kernel
// 256 wgs x 256 thr; wg w owns h-dims {2w, 2w+1} and attn-cols {2w, 2w+1}.
// Stages per step: S1 gates->h_new | S2 pq (+ctx zero) | S3 scores/softmax-partials | S4 context+attn_new
__global__ __launch_bounds__(THR) void recur_kernel(
    const float* __restrict__ Ex, const float* __restrict__ keys,
    const float* __restrict__ memg, const float* __restrict__ v_att,
    const float* __restrict__ gbias,
    const float* __restrict__ KbT, const float* __restrict__ RT,
    const float* __restrict__ WqT, const float* __restrict__ WaT,
    float* act, float* hnew, float* pq, float* ctx, float* den,
    unsigned short* attnall, unsigned int* flags) {
  extern __shared__ float sm[];
  float* wKf    = sm;              // 3072: K_botT rows [g*2+dd][512]
  float* wRf    = wKf + 3072;      // 3072
  float* wqf    = wRf + 3072;      // 1024: WqT rows j
  float* wAf    = wqf + 1024;      // 2048: WaT rows j
  float* vvf    = wAf + 2048;      // 512
  float* stagef = vvf + 512;       // 8192 (32x256 chunk; aliased as reduce scratch)
  float* redf   = stagef + 8192;   // 512
  float* esf    = redf + 512;      // 64
  float* pqsf   = esf + 64;        // 512

  const int w = blockIdx.x;
  const int tid = threadIdx.x;

  // persist per-wg weight slices
  for (int i = tid; i < 3072; i += THR) {
    int gd = i >> 9, k = i & 511;
    int c = ((gd >> 1) << 9) + 2*w + (gd & 1);
    wKf[i] = KbT[c*512 + k];
    wRf[i] = RT[c*512 + k];
  }
  for (int i = tid; i < 1024; i += THR) {
    int jj = i >> 9, k = i & 511;
    wqf[i] = WqT[(2*w + jj)*512 + k];
  }
  for (int i = tid; i < 2048; i += THR) {
    int jj = i >> 10, k = i & 1023;
    wAf[i] = WaT[(2*w + jj)*1024 + k];
  }
  for (int i = tid; i < 512; i += THR) vvf[i] = v_att[i];
  __syncthreads();

  unsigned int ep = 0;
  const int sb = w >> 3, ssc = w & 7;  // S3: (batch, s-chunk)

  for (int t = 0; t < TT; ++t) {
    const int p = t & 1;
    const float* hprev = hnew + p*(BB*UU);
    float* hcur = hnew + (p ^ 1)*(BB*UU);

    // ---------------- S1: gates + h_new ----------------
    {
      float4 accD0[8], accD1[8];
#pragma unroll
      for (int bb = 0; bb < 8; ++bb) {
        accD0[bb] = make_float4(0,0,0,0); accD1[bb] = make_float4(0,0,0,0);
      }
      const int bq = (tid >> 5) & 3;
      const int ks = tid & 31;
      for (int ch = 0; ch < 4; ++ch) {
        __syncthreads();
        float4* st4 = (float4*)stagef;
#pragma unroll
        for (int j2 = 0; j2 < 8; ++j2) {
          int i = tid + j2*256;
          int b = i >> 6, gr = i & 63;
          st4[i] = *(const float4*)(act + b*1024 + ch*256 + gr*4);
        }
        __syncthreads();
        if (tid < 128) {
          const float* wH = (ch < 2) ? wKf : wRf;
#pragma unroll
          for (int ii = 0; ii < 2; ++ii) {
            int gr = ks + 32*ii;
            int kf = (((ch & 1) << 6) + gr)*4;  // float offset within 512-half
            float4 wz0 = *(const float4*)&wH[0*512 + kf];
            float4 wz1 = *(const float4*)&wH[1*512 + kf];
            float4 wr0 = *(const float4*)&wH[2*512 + kf];
            float4 wr1 = *(const float4*)&wH[3*512 + kf];
            float4 wh0 = *(const float4*)&wH[4*512 + kf];
            float4 wh1 = *(const float4*)&wH[5*512 + kf];
#pragma unroll
            for (int bb = 0; bb < 8; ++bb) {
              float4 a = *(const float4*)&stagef[((bq*8 + bb)*64 + gr)*4];
              accD0[bb].x += d4(a, wz0);
              accD0[bb].y += d4(a, wr0);
              accD1[bb].x += d4(a, wz1);
              accD1[bb].y += d4(a, wr1);
              float h0 = d4(a, wh0), h1 = d4(a, wh1);
              if (ch < 2) { accD0[bb].z += h0; accD1[bb].z += h1; }
              else        { accD0[bb].w += h0; accD1[bb].w += h1; }
            }
          }
        }
      }
      __syncthreads();
      float4* P4 = (float4*)stagef;
      if (tid < 128) {
#pragma unroll
        for (int bb = 0; bb < 8; ++bb) {
          int b = bq*8 + bb;
          P4[ks*64 + b*2 + 0] = accD0[bb];
          P4[ks*64 + b*2 + 1] = accD1[bb];
        }
      }
      __syncthreads();
      if (tid < 64) {
        int b = tid >> 1, dd = tid & 1;
        float4 s = make_float4(0,0,0,0);
        for (int k2 = 0; k2 < 32; ++k2) {
          float4 v = P4[k2*64 + b*2 + dd];
          s.x += v.x; s.y += v.y; s.z += v.z; s.w += v.w;
        }
        int d = 2*w + dd;
        const float* exr = Ex + (size_t)(t*BB + b)*1536;
        float xz  = exr[d]        + gbias[1536 + d]        + s.x;
        float xr  = exr[512 + d]  + gbias[1536 + 512 + d]  + s.y;
        float xh  = exr[1024 + d] + s.z;
        float hhr = s.w + gbias[1536 + 1024 + d];
        float z = sigm(xz), r = sigm(xr);
        float hh = tanh_(xh + r*hhr);
        float hp = hprev[b*UU + d];
        hcur[b*UU + d] = z*hp + (1.f - z)*hh;
      }
    }
    gbar(flags, ++ep, tid, w);

    // ---------------- S2: pq = h_new @ Wq; zero ctx/den ----------------
    {
      const int b = tid & 31, ks8 = tid >> 5;
      const int k0 = ks8*64;
      float a0 = 0.f, a1 = 0.f;
      for (int i = 0; i < 16; ++i) {
        float4 h4 = *(const float4*)(hcur + b*UU + k0 + i*4);
        float4 q0 = *(const float4*)&wqf[0*512 + k0 + i*4];
        float4 q1 = *(const float4*)&wqf[1*512 + k0 + i*4];
        a0 += d4(h4, q0); a1 += d4(h4, q1);
      }
      float2* P2 = (float2*)stagef;
      P2[b*8 + ks8] = make_float2(a0, a1);
      __syncthreads();
      if (tid < 32) {
        float s0 = 0.f, s1 = 0.f;
        for (int k2 = 0; k2 < 8; ++k2) { float2 v = P2[tid*8 + k2]; s0 += v.x; s1 += v.y; }
        pq[tid*UU + 2*w] = s0; pq[tid*UU + 2*w + 1] = s1;
      }
      if (tid < 64) ctx[(w << 6) + tid] = 0.f;
      if (w < 32 && tid == 0) den[w] = 0.f;
    }
    gbar(flags, ++ep, tid, w);

    // ---------------- S3: scores / exp / context partials ----------------
    {
      if (tid < 128) *(float4*)&pqsf[tid*4] = *(const float4*)(pq + sb*UU + tid*4);
      __syncthreads();
      const int sl = tid >> 4, ug = tid & 15;
      float a = 0.f;
      {
        const float* kr = keys + ((size_t)(sb*SS) + ssc*16 + sl)*UU + ug*32;
        const float* pr = pqsf + ug*32;
        const float* vr = vvf + ug*32;
        for (int i = 0; i < 8; ++i) {
          float4 kk = *(const float4*)(kr + i*4);
          float4 pp = *(const float4*)(pr + i*4);
          float4 v4 = *(const float4*)(vr + i*4);
          a += v4.x*tanh_(kk.x + pp.x) + v4.y*tanh_(kk.y + pp.y)
             + v4.z*tanh_(kk.z + pp.z) + v4.w*tanh_(kk.w + pp.w);
        }
      }
      redf[sl*17 + ug] = a;
      __syncthreads();
      if (tid < 16) {
        float sc = 0.f;
        for (int i = 0; i < 16; ++i) sc += redf[tid*17 + i];
        esf[tid] = __expf(sc);  // scores bounded (|score| <= sum|v| ~ 8), no max-sub needed
      }
      __syncthreads();
      if (tid == 0) {
        float d = 0.f;
        for (int i = 0; i < 16; ++i) d += esf[i];
        atomicAdd(&den[sb], d);
      }
      {
        const int u0 = tid*2;
        float c0 = 0.f, c1 = 0.f;
        for (int sl2 = 0; sl2 < 16; ++sl2) {
          float e = esf[sl2];
          float2 m2 = *(const float2*)(memg + ((size_t)(sb*SS) + ssc*16 + sl2)*UU + u0);
          c0 += e*m2.x; c1 += e*m2.y;
        }
        atomicAdd(&ctx[sb*UU + u0], c0);
        atomicAdd(&ctx[sb*UU + u0 + 1], c1);
      }
    }
    gbar(flags, ++ep, tid, w);

    // ---------------- S4: attn_new = [h_new, ctx/den] @ Wa ----------------
    {
      float2 accH[8], accC[8];
#pragma unroll
      for (int bb = 0; bb < 8; ++bb) { accH[bb] = make_float2(0,0); accC[bb] = make_float2(0,0); }
      const int bq = (tid >> 5) & 3;
      const int ks = tid & 31;
      for (int ch = 0; ch < 4; ++ch) {
        __syncthreads();
        const float* src = (ch < 2) ? (hcur + ch*256) : (ctx + (ch - 2)*256);
        float4* st4 = (float4*)stagef;
#pragma unroll
        for (int j2 = 0; j2 < 8; ++j2) {
          int i = tid + j2*256;
          int b = i >> 6, gr = i & 63;
          st4[i] = *(const float4*)(src + b*512 + gr*4);
        }
        __syncthreads();
        if (tid < 128) {
          int kbase = (ch < 2) ? ch*256 : (512 + (ch - 2)*256);
#pragma unroll
          for (int ii = 0; ii < 2; ++ii) {
            int gr = ks + 32*ii;
            float4 w0 = *(const float4*)&wAf[0*1024 + kbase + gr*4];
            float4 w1 = *(const float4*)&wAf[1*1024 + kbase + gr*4];
#pragma unroll
            for (int bb = 0; bb < 8; ++bb) {
              float4 a = *(const float4*)&stagef[((bq*8 + bb)*64 + gr)*4];
              float v0 = d4(a, w0), v1 = d4(a, w1);
              if (ch < 2) { accH[bb].x += v0; accH[bb].y += v1; }
              else        { accC[bb].x += v0; accC[bb].y += v1; }
            }
          }
        }
      }
      __syncthreads();
      float2* P2 = (float2*)stagef;
      if (tid < 128) {
#pragma unroll
        for (int bb = 0; bb < 8; ++bb) {
          int b = bq*8 + bb;
          P2[ks*32 + b] = accH[bb];
          P2[1024 + ks*32 + b] = accC[bb];
        }
      }
      __syncthreads();
      if (tid < 32) {
        int b = tid;
        float shx = 0.f, shy = 0.f, scx = 0.f, scy = 0.f;
        for (int k2 = 0; k2 < 32; ++k2) {
          float2 vh = P2[k2*32 + b];        shx += vh.x; shy += vh.y;
          float2 vc = P2[1024 + k2*32 + b]; scx += vc.x; scy += vc.y;
        }
        float dn = den[b];
        float aj0 = shx + scx/dn;
        float aj1 = shy + scy/dn;
        act[b*1024 + 2*w]     = aj0;
        act[b*1024 + 2*w + 1] = aj1;
        attnall[(size_t)(b*TT + t)*UU + 2*w]     = f2bf(aj0);
        attnall[(size_t)(b*TT + t)*UU + 2*w + 1] = f2bf(aj1);
        act[b*1024 + 512 + 2*w]     = hcur[b*UU + 2*w];
        act[b*1024 + 512 + 2*w + 1] = hcur[b*UU + 2*w + 1];
      }
    }
    if (t != TT - 1) gbar(flags, ++ep, tid, w);
  }
}

// ---------------------------------------------------------------- launch
extern "C" void kernel_launch(void* const* d_in, const int* in_sizes, int n_in,
                              void* d_out, int out_size, void* d_ws, size_t ws_size,
                              hipStream_t stream) {
  const int*   x    = (const int*)d_in[0];
  const float* enc  = (const float*)d_in[1];
  const float* memf = (const float*)d_in[2];
  const float* E    = (const float*)d_in[3];
  const float* Kk   = (const float*)d_in[4];
  const float* Rk   = (const float*)d_in[5];
  const float* gb   = (const float*)d_in[6];
  const float* Wq   = (const float*)d_in[7];
  const float* Wk   = (const float*)d_in[8];
  const float* va   = (const float*)d_in[9];
  const float* Wa   = (const float*)d_in[10];
  const float* Wo   = (const float*)d_in[11];
  const float* bo   = (const float*)d_in[12];
  float* out = (float*)d_out;
  (void)in_sizes; (void)n_in; (void)out_size; (void)ws_size;

  char* ws = (char*)d_ws;
  size_t off = 0;
  auto alloc = [&](size_t bytes) -> char* {
    char* p = ws + off; off = (off + bytes + 255) & ~(size_t)255; return p;
  };
  unsigned int* flags = (unsigned int*)alloc(NW*4);
  float* act   = (float*)alloc((size_t)BB*1024*4);
  float* hnew  = (float*)alloc((size_t)2*BB*UU*4);
  float* pq    = (float*)alloc((size_t)BB*UU*4);
  float* ctx   = (float*)alloc((size_t)BB*UU*4);
  float* den   = (float*)alloc((size_t)BB*4);
  float* Ex    = (float*)alloc((size_t)2016*1536*4);
  float* keys  = (float*)alloc((size_t)BB*SS*UU*4);
  unsigned short* membf = (unsigned short*)alloc((size_t)BB*SS*UU*2);
  unsigned short* embg  = (unsigned short*)alloc((size_t)2048*EMBD*2);
  unsigned short* KtT   = (unsigned short*)alloc((size_t)1536*EMBD*2);
  unsigned short* WkT   = (unsigned short*)alloc((size_t)UU*UU*2);
  unsigned short* WoT   = (unsigned short*)alloc((size_t)VV*UU*2);
  float* KbT  = (float*)alloc((size_t)1536*512*4);
  float* RTm  = (float*)alloc((size_t)1536*512*4);
  float* WqT  = (float*)alloc((size_t)512*512*4);
  float* WaT  = (float*)alloc((size_t)512*1024*4);
  unsigned short* attnall = (unsigned short*)alloc((size_t)2048*UU*2);
  // total ~72 MB of workspace

  init_kernel<<<512, 256, 0, stream>>>(flags, act, hnew, attnall, embg, enc);
  conv_bf16<<<(BB*SS*UU)/256, 256, 0, stream>>>(memf, membf, BB*SS*UU);
  gather_emb<<<2016, 256, 0, stream>>>(x, E, embg);
  transpose_f32<<<dim3(48,16), 256, 0, stream>>>(Kk + 256*1536, KbT, 512, 1536);  // K_bot^T
  transpose_f32<<<dim3(48,16), 256, 0, stream>>>(Rk, RTm, 512, 1536);
  transpose_f32<<<dim3(16,16), 256, 0, stream>>>(Wq, WqT, 512, 512);
  transpose_f32<<<dim3(16,32), 256, 0, stream>>>(Wa, WaT, 1024, 512);
  transpose_bf16<<<dim3(48,8), 256, 0, stream>>>(Kk, KtT, 256, 1536);             // K_top^T
  transpose_bf16<<<dim3(16,16), 256, 0, stream>>>(Wk, WkT, 512, 512);
  transpose_bf16<<<dim3(1000,16), 256, 0, stream>>>(Wo, WoT, 512, 32000);

  // keys = memory @ Wk  : [4096,512]@[512,512]
  gemm_bf16<<<dim3(4,32), 256, 0, stream>>>(membf, WkT, nullptr, keys, 4096, 512, 512);
  // Ex = emb @ K_top + bias0 : [2016,256]@[256,1536]
  gemm_bf16<<<dim3(12,16), 256, 0, stream>>>(embg, KtT, gb, Ex, 2016, 256, 1536);

  hipFuncSetAttribute((const void*)recur_kernel,
                      hipFuncAttributeMaxDynamicSharedMemorySize, 76032);
  recur_kernel<<<NW, THR, 76032, stream>>>(Ex, keys, memf, va, gb, KbT, RTm, WqT, WaT,
                                           act, hnew, pq, ctx, den, attnall, flags);

  // logits = attn_all @ Wo + bo : [2016,512]@[512,32000]
  gemm_bf16<<<dim3(250,16), 256, 0, stream>>>(attnall, WoT, bo, out, 2016, 512, VV);
}

// Round 2
// 4675.945 us; speedup vs baseline: 2.4344x; 2.4344x over previous
//
#include <hip/hip_runtime.h>
#include <hip/hip_bf16.h>
#include <stdint.h>

#define BB 32      // batch
#define SS 128     // memory length
#define TT 63      // time steps
#define UU 512     // units
#define EMBD 256
#define VV 32000
#define NW 256     // workgroups in persistent recurrence kernel
#define THR 256

typedef __attribute__((ext_vector_type(8))) short short8;
typedef __attribute__((ext_vector_type(4))) float f32x4;

static __device__ __forceinline__ unsigned short f2bf(float f) {
  union { float f; unsigned int u; } c; c.f = f;
  unsigned int u = c.u;
  unsigned int r = (u + 0x7FFFu + ((u >> 16) & 1u)) >> 16;  // RNE
  return (unsigned short)r;
}
static __device__ __forceinline__ float d4(float4 a, float4 b) {
  return a.x*b.x + a.y*b.y + a.z*b.z + a.w*b.w;
}
static __device__ __forceinline__ float sigm(float x) { return 1.f/(1.f + __expf(-x)); }
static __device__ __forceinline__ float tanh_(float x) { return 1.f - 2.f/(__expf(2.f*x) + 1.f); }

// -------- coherent (write-through, L1/L2-bypass) access helpers ----------
static __device__ __forceinline__ float cload(const float* p) {
  return __hip_atomic_load(p, __ATOMIC_RELAXED, __HIP_MEMORY_SCOPE_AGENT);
}
static __device__ __forceinline__ float2 cload2(const float2* p) {
  unsigned long long v = __hip_atomic_load((const unsigned long long*)p,
                                           __ATOMIC_RELAXED, __HIP_MEMORY_SCOPE_AGENT);
  union { unsigned long long u; float2 f; } c; c.u = v; return c.f;
}
static __device__ __forceinline__ void cstore(float* p, float v) {
  __hip_atomic_store(p, v, __ATOMIC_RELAXED, __HIP_MEMORY_SCOPE_AGENT);
}

// ---------------------------------------------------------------- init
__global__ void init_kernel(unsigned int* flags, float* act, float* hnew0,
                            unsigned short* attnall, unsigned short* embg,
                            const float* enc) {
  int idx = blockIdx.x*blockDim.x + threadIdx.x;
  int stride = gridDim.x*blockDim.x;
  const int total = NW + BB*1024 + BB*UU + 32*UU + 32*EMBD;
  for (int i = idx; i < total; i += stride) {
    int j = i;
    if (j < NW) { flags[j] = 0u; continue; } j -= NW;
    if (j < BB*1024) { int b = j >> 10, c = j & 1023;
      act[j] = (c < UU) ? 0.f : enc[b*UU + (c - UU)]; continue; } j -= BB*1024;
    if (j < BB*UU) { hnew0[j] = enc[j]; continue; } j -= BB*UU;
    if (j < 32*UU) { attnall[2016*UU + j] = 0; continue; } j -= 32*UU;
    embg[2016*EMBD + j] = 0;
  }
}

// ---------------------------------------------------------------- elementwise converts
__global__ void conv_bf16(const float* __restrict__ in, unsigned short* __restrict__ out, int n) {
  int i = blockIdx.x*blockDim.x + threadIdx.x;
  if (i < n) out[i] = f2bf(in[i]);
}

__global__ void gather_emb(const int* __restrict__ x, const float* __restrict__ E,
                           unsigned short* __restrict__ embg) {
  int idx = blockIdx.x*blockDim.x + threadIdx.x;  // 2016*256 exact
  int m = idx >> 8, k = idx & 255;
  int t = m >> 5, b = m & 31;                     // m = t*32 + b
  int xi = x[b*TT + t];
  embg[m*EMBD + k] = f2bf(E[(size_t)xi*EMBD + k]);
}

// ---------------------------------------------------------------- transposes
__global__ void transpose_f32(const float* __restrict__ in, float* __restrict__ out, int R, int Cc) {
  __shared__ float tile[32][33];
  int bx = blockIdx.x*32, by = blockIdx.y*32;
  int tx = threadIdx.x & 31, ty = threadIdx.x >> 5;
  for (int i = 0; i < 4; ++i) {
    int r = by + ty + i*8;
    if (r < R && bx + tx < Cc) tile[ty + i*8][tx] = in[(size_t)r*Cc + bx + tx];
  }
  __syncthreads();
  for (int i = 0; i < 4; ++i) {
    int c = bx + ty + i*8;
    if (c < Cc && by + tx < R) out[(size_t)c*R + by + tx] = tile[tx][ty + i*8];
  }
}

__global__ void transpose_bf16(const float* __restrict__ in, unsigned short* __restrict__ out, int R, int Cc) {
  __shared__ float tile[32][33];
  int bx = blockIdx.x*32, by = blockIdx.y*32;
  int tx = threadIdx.x & 31, ty = threadIdx.x >> 5;
  for (int i = 0; i < 4; ++i) {
    int r = by + ty + i*8;
    if (r < R && bx + tx < Cc) tile[ty + i*8][tx] = in[(size_t)r*Cc + bx + tx];
  }
  __syncthreads();
  for (int i = 0; i < 4; ++i) {
    int c = bx + ty + i*8;
    if (c < Cc && by + tx < R) out[(size_t)c*R + by + tx] = f2bf(tile[tx][ty + i*8]);
  }
}

// ---------------------------------------------------------------- generic bf16 MFMA GEMM
__global__ __launch_bounds__(256) void gemm_bf16(
    const unsigned short* __restrict__ A, const unsigned short* __restrict__ Bt,
    const float* __restrict__ bias, float* __restrict__ C,
    int Mreal, int K, int N) {
  __shared__ __align__(16) unsigned short As[128*48];
  __shared__ __align__(16) unsigned short Bs[128*48];
  const int tid = threadIdx.x;
  const int m0 = blockIdx.y*128, n0 = blockIdx.x*128;
  const int wave = tid >> 6, lane = tid & 63;
  const int wm = (wave >> 1)*64, wn = (wave & 1)*64;
  const int fr = lane & 15, kq = (lane >> 4)*8, quad = lane >> 4;
  f32x4 acc[4][4];
#pragma unroll
  for (int mt = 0; mt < 4; ++mt)
#pragma unroll
    for (int nt = 0; nt < 4; ++nt) acc[mt][nt] = (f32x4){0.f, 0.f, 0.f, 0.f};
  const int nkt = K >> 5;
  for (int kt = 0; kt < nkt; ++kt) {
    __syncthreads();
#pragma unroll
    for (int i = 0; i < 2; ++i) {
      int g = tid + i*256;
      int r = g >> 2, seg = g & 3;
      *(uint4*)&As[r*48 + seg*8] = *(const uint4*)&A[(size_t)(m0 + r)*K + kt*32 + seg*8];
      *(uint4*)&Bs[r*48 + seg*8] = *(const uint4*)&Bt[(size_t)(n0 + r)*K + kt*32 + seg*8];
    }
    __syncthreads();
    short8 af[4], bf[4];
#pragma unroll
    for (int mt = 0; mt < 4; ++mt) af[mt] = *(const short8*)&As[(wm + mt*16 + fr)*48 + kq];
#pragma unroll
    for (int nt = 0; nt < 4; ++nt) bf[nt] = *(const short8*)&Bs[(wn + nt*16 + fr)*48 + kq];
#pragma unroll
    for (int mt = 0; mt < 4; ++mt)
#pragma unroll
      for (int nt = 0; nt < 4; ++nt)
        acc[mt][nt] = __builtin_amdgcn_mfma_f32_16x16x32_bf16(af[mt], bf[nt], acc[mt][nt], 0, 0, 0);
  }
#pragma unroll
  for (int mt = 0; mt < 4; ++mt) {
    int mb = m0 + wm + mt*16 + quad*4;
#pragma unroll
    for (int nt = 0; nt < 4; ++nt) {
      int ng = n0 + wn + nt*16 + fr;
      float bv = bias ? bias[ng] : 0.f;
#pragma unroll
      for (int reg = 0; reg < 4; ++reg) {
        int mg = mb + reg;
        if (mg < Mreal) C[(size_t)mg*N + ng] = acc[mt][nt][reg] + bv;
      }
    }
  }
}

// ---------------------------------------------------------------- grid barrier
// monotonic counter arrive + generation broadcast; one poller thread per wg.
// Release: per-wave s_waitcnt vmcnt(0) (all mutable data uses write-through
// coherent stores, so no L2 writeback/invalidate is needed).
static __device__ __forceinline__ void gbar(unsigned int* flags, unsigned int ep, int tid) {
  asm volatile("s_waitcnt vmcnt(0)" ::: "memory");   // each wave drains its stores
  __syncthreads();
  if (tid == 0) {
    unsigned int old = __hip_atomic_fetch_add(&flags[0], 1u,
                                              __ATOMIC_RELAXED, __HIP_MEMORY_SCOPE_AGENT);
    if (old == ep*(unsigned)NW - 1u) {
      __hip_atomic_store(&flags[64], ep, __ATOMIC_RELAXED, __HIP_MEMORY_SCOPE_AGENT);
    } else {
      while (__hip_atomic_load(&flags[64], __ATOMIC_RELAXED, __HIP_MEMORY_SCOPE_AGENT) < ep)
        __builtin_amdgcn_s_sleep(2);
    }
  }
  __syncthreads();
  asm volatile("" ::: "memory");
}

// ---------------------------------------------------------------- persistent recurrence kernel
__global__ __launch_bounds__(THR) void recur_kernel(
    const float* __restrict__ Ex, const float* __restrict__ keys,
    const float* __restrict__ memg, const float* __restrict__ v_att,
    const float* __restrict__ gbias,
    const float* __restrict__ KbT, const float* __restrict__ RT,
    const float* __restrict__ WqT, const float* __restrict__ WaT,
    float* act, float* hnew, float* pq, float* ctx, float* den,
    unsigned short* attnall, unsigned int* flags) {
  extern __shared__ float sm[];
  float* wKf    = sm;              // 3072
  float* wRf    = wKf + 3072;      // 3072
  float* wqf    = wRf + 3072;      // 1024
  float* wAf    = wqf + 1024;      // 2048
  float* vvf    = wAf + 2048;      // 512
  float* stagef = vvf + 512;       // 8192
  float* redf   = stagef + 8192;   // 512
  float* esf    = redf + 512;      // 64
  float* pqsf   = esf + 64;        // 512

  const int w = blockIdx.x;
  const int tid = threadIdx.x;

  for (int i = tid; i < 3072; i += THR) {
    int gd = i >> 9, k = i & 511;
    int c = ((gd >> 1) << 9) + 2*w + (gd & 1);
    wKf[i] = KbT[c*512 + k];
    wRf[i] = RT[c*512 + k];
  }
  for (int i = tid; i < 1024; i += THR) {
    int jj = i >> 9, k = i & 511;
    wqf[i] = WqT[(2*w + jj)*512 + k];
  }
  for (int i = tid; i < 2048; i += THR) {
    int jj = i >> 10, k = i & 1023;
    wAf[i] = WaT[(2*w + jj)*1024 + k];
  }
  for (int i = tid; i < 512; i += THR) vvf[i] = v_att[i];
  __syncthreads();

  unsigned int ep = 0;
  const int sb = w >> 3, ssc = w & 7;

  for (int t = 0; t < TT; ++t) {
    const int p = t & 1;
    const float* hprev = hnew + p*(BB*UU);
    float* hcur = hnew + (p ^ 1)*(BB*UU);

    // ---------------- S1: gates + h_new ----------------
    {
      float4 accD0[8], accD1[8];
#pragma unroll
      for (int bb = 0; bb < 8; ++bb) {
        accD0[bb] = make_float4(0,0,0,0); accD1[bb] = make_float4(0,0,0,0);
      }
      const int bq = (tid >> 5) & 3;
      const int ks = tid & 31;
      for (int ch = 0; ch < 4; ++ch) {
        __syncthreads();
        float2* st2 = (float2*)stagef;
#pragma unroll
        for (int j2 = 0; j2 < 16; ++j2) {
          int j = tid + j2*256;
          int b = j >> 7, rr = j & 127;
          st2[j] = cload2((const float2*)(act + b*1024 + ch*256) + rr);
        }
        __syncthreads();
        if (tid < 128) {
          const float* wH = (ch < 2) ? wKf : wRf;
#pragma unroll
          for (int ii = 0; ii < 2; ++ii) {
            int gr = ks + 32*ii;
            int kf = (((ch & 1) << 6) + gr)*4;
            float4 wz0 = *(const float4*)&wH[0*512 + kf];
            float4 wz1 = *(const float4*)&wH[1*512 + kf];
            float4 wr0 = *(const float4*)&wH[2*512 + kf];
            float4 wr1 = *(const float4*)&wH[3*512 + kf];
            float4 wh0 = *(const float4*)&wH[4*512 + kf];
            float4 wh1 = *(const float4*)&wH[5*512 + kf];
#pragma unroll
            for (int bb = 0; bb < 8; ++bb) {
              float4 a = *(const float4*)&stagef[((bq*8 + bb)*64 + gr)*4];
              accD0[bb].x += d4(a, wz0);
              accD0[bb].y += d4(a, wr0);
              accD1[bb].x += d4(a, wz1);
              accD1[bb].y += d4(a, wr1);
              float h0 = d4(a, wh0), h1 = d4(a, wh1);
              if (ch < 2) { accD0[bb].z += h0; accD1[bb].z += h1; }
              else        { accD0[bb].w += h0; accD1[bb].w += h1; }
            }
          }
        }
      }
      __syncthreads();
      float4* P4 = (float4*)stagef;
      if (tid < 128) {
#pragma unroll
        for (int bb = 0; bb < 8; ++bb) {
          int b = bq*8 + bb;
          P4[ks*64 + b*2 + 0] = accD0[bb];
          P4[ks*64 + b*2 + 1] = accD1[bb];
        }
      }
      __syncthreads();
      if (tid < 64) {
        int b = tid >> 1, dd = tid & 1;
        float4 s = make_float4(0,0,0,0);
        for (int k2 = 0; k2 < 32; ++k2) {
          float4 v = P4[k2*64 + b*2 + dd];
          s.x += v.x; s.y += v.y; s.z += v.z; s.w += v.w;
        }
        int d = 2*w + dd;
        const float* exr = Ex + (size_t)(t*BB + b)*1536;
        float xz  = exr[d]        + gbias[1536 + d]        + s.x;
        float xr  = exr[512 + d]  + gbias[1536 + 512 + d]  + s.y;
        float xh  = exr[1024 + d] + s.z;
        float hhr = s.w + gbias[1536 + 1024 + d];
        float z = sigm(xz), r = sigm(xr);
        float hh = tanh_(xh + r*hhr);
        float hp = cload(hprev + b*UU + d);
        cstore(hcur + b*UU + d, z*hp + (1.f - z)*hh);
      }
    }
    gbar(flags, ++ep, tid);

    // ---------------- S2: pq = h_new @ Wq; zero ctx/den ----------------
    {
      const int b = tid & 31, ks8 = tid >> 5;
      const int k0 = ks8*64;
      float a0 = 0.f, a1 = 0.f;
      for (int i = 0; i < 32; ++i) {
        float2 h2 = cload2((const float2*)(hcur + b*UU + k0) + i);
        float2 q0 = *(const float2*)&wqf[0*512 + k0 + i*2];
        float2 q1 = *(const float2*)&wqf[1*512 + k0 + i*2];
        a0 += h2.x*q0.x + h2.y*q0.y;
        a1 += h2.x*q1.x + h2.y*q1.y;
      }
      float2* P2 = (float2*)stagef;
      P2[b*8 + ks8] = make_float2(a0, a1);
      __syncthreads();
      if (tid < 32) {
        float s0 = 0.f, s1 = 0.f;
        for (int k2 = 0; k2 < 8; ++k2) { float2 v = P2[tid*8 + k2]; s0 += v.x; s1 += v.y; }
        cstore(pq + tid*UU + 2*w, s0);
        cstore(pq + tid*UU + 2*w + 1, s1);
      }
      if (tid < 64) cstore(ctx + (w << 6) + tid, 0.f);
      if (w < 32 && tid == 0) cstore(den + w, 0.f);
    }
    gbar(flags, ++ep, tid);

    // ---------------- S3: scores / exp / context partials ----------------
    {
      if (tid < 128) {
        float2* dst = (float2*)&pqsf[tid*4];
        dst[0] = cload2((const float2*)(pq + sb*UU + tid*4));
        dst[1] = cload2((const float2*)(pq + sb*UU + tid*4 + 2));
      }
      __syncthreads();
      const int sl = tid >> 4, ug = tid & 15;
      float a = 0.f;
      {
        const float* kr = keys + ((size_t)(sb*SS) + ssc*16 + sl)*UU + ug*32;
        const float* pr = pqsf + ug*32;
        const float* vr = vvf + ug*32;
        for (int i = 0; i < 8; ++i) {
          float4 kk = *(const float4*)(kr + i*4);
          float4 pp = *(const float4*)(pr + i*4);
          float4 v4 = *(const float4*)(vr + i*4);
          a += v4.x*tanh_(kk.x + pp.x) + v4.y*tanh_(kk.y + pp.y)
             + v4.z*tanh_(kk.z + pp.z) + v4.w*tanh_(kk.w + pp.w);
        }
      }
      redf[sl*17 + ug] = a;
      __syncthreads();
      if (tid < 16) {
        float sc = 0.f;
        for (int i = 0; i < 16; ++i) sc += redf[tid*17 + i];
        esf[tid] = __expf(sc);
      }
      __syncthreads();
      if (tid == 0) {
        float d = 0.f;
        for (int i = 0; i < 16; ++i) d += esf[i];
        atomicAdd(&den[sb], d);
      }
      {
        const int u0 = tid*2;
        float c0 = 0.f, c1 = 0.f;
        for (int sl2 = 0; sl2 < 16; ++sl2) {
          float e = esf[sl2];
          float2 m2 = *(const float2*)(memg + ((size_t)(sb*SS) + ssc*16 + sl2)*UU + u0);
          c0 += e*m2.x; c1 += e*m2.y;
        }
        atomicAdd(&ctx[sb*UU + u0], c0);
        atomicAdd(&ctx[sb*UU + u0 + 1], c1);
      }
    }
    gbar(flags, ++ep, tid);

    // ---------------- S4: attn_new = [h_new, ctx/den] @ Wa ----------------
    {
      float2 accH[8], accC[8];
#pragma unroll
      for (int bb = 0; bb < 8; ++bb) { accH[bb] = make_float2(0,0); accC[bb] = make_float2(0,0); }
      const int bq = (tid >> 5) & 3;
      const int ks = tid & 31;
      for (int ch = 0; ch < 4; ++ch) {
        __syncthreads();
        const float* src = (ch < 2) ? (hcur + ch*256) : (ctx + (ch - 2)*256);
        float2* st2 = (float2*)stagef;
#pragma unroll
        for (int j2 = 0; j2 < 16; ++j2) {
          int j = tid + j2*256;
          int b = j >> 7, rr = j & 127;
          st2[j] = cload2((const float2*)(src + b*512) + rr);
        }
        __syncthreads();
        if (tid < 128) {
          int kbase = (ch < 2) ? ch*256 : (512 + (ch - 2)*256);
#pragma unroll
          for (int ii = 0; ii < 2; ++ii) {
            int gr = ks + 32*ii;
            float4 w0 = *(const float4*)&wAf[0*1024 + kbase + gr*4];
            float4 w1 = *(const float4*)&wAf[1*1024 + kbase + gr*4];
#pragma unroll
            for (int bb = 0; bb < 8; ++bb) {
              float4 a = *(const float4*)&stagef[((bq*8 + bb)*64 + gr)*4];
              float v0 = d4(a, w0), v1 = d4(a, w1);
              if (ch < 2) { accH[bb].x += v0; accH[bb].y += v1; }
              else        { accC[bb].x += v0; accC[bb].y += v1; }
            }
          }
        }
      }
      __syncthreads();
      float2* P2 = (float2*)stagef;
      if (tid < 128) {
#pragma unroll
        for (int bb = 0; bb < 8; ++bb) {
          int b = bq*8 + bb;
          P2[ks*32 + b] = accH[bb];
          P2[1024 + ks*32 + b] = accC[bb];
        }
      }
      __syncthreads();
      if (tid < 32) {
        int b = tid;
        float shx = 0.f, shy = 0.f, scx = 0.f, scy = 0.f;
        for (int k2 = 0; k2 < 32; ++k2) {
          float2 vh = P2[k2*32 + b];        shx += vh.x; shy += vh.y;
          float2 vc = P2[1024 + k2*32 + b]; scx += vc.x; scy += vc.y;
        }
        float dn = cload(den + b);
        float aj0 = shx + scx/dn;
        float aj1 = shy + scy/dn;
        cstore(act + b*1024 + 2*w, aj0);
        cstore(act + b*1024 + 2*w + 1, aj1);
        attnall[(size_t)(b*TT + t)*UU + 2*w]     = f2bf(aj0);
        attnall[(size_t)(b*TT + t)*UU + 2*w + 1] = f2bf(aj1);
        cstore(act + b*1024 + 512 + 2*w, cload(hcur + b*UU + 2*w));
        cstore(act + b*1024 + 512 + 2*w + 1, cload(hcur + b*UU + 2*w + 1));
      }
    }
    if (t != TT - 1) gbar(flags, ++ep, tid);
  }
}

// ---------------------------------------------------------------- launch
extern "C" void kernel_launch(void* const* d_in, const int* in_sizes, int n_in,
                              void* d_out, int out_size, void* d_ws, size_t ws_size,
                              hipStream_t stream) {
  const int*   x    = (const int*)d_in[0];
  const float* enc  = (const float*)d_in[1];
  const float* memf = (const float*)d_in[2];
  const float* E    = (const float*)d_in[3];
  const float* Kk   = (const float*)d_in[4];
  const float* Rk   = (const float*)d_in[5];
  const float* gb   = (const float*)d_in[6];
  const float* Wq   = (const float*)d_in[7];
  const float* Wk   = (const float*)d_in[8];
  const float* va   = (const float*)d_in[9];
  const float* Wa   = (const float*)d_in[10];
  const float* Wo   = (const float*)d_in[11];
  const float* bo   = (const float*)d_in[12];
  float* out = (float*)d_out;
  (void)in_sizes; (void)n_in; (void)out_size; (void)ws_size;

  char* ws = (char*)d_ws;
  size_t off = 0;
  auto alloc = [&](size_t bytes) -> char* {
    char* p = ws + off; off = (off + bytes + 255) & ~(size_t)255; return p;
  };
  unsigned int* flags = (unsigned int*)alloc(NW*4);
  float* act   = (float*)alloc((size_t)BB*1024*4);
  float* hnew  = (float*)alloc((size_t)2*BB*UU*4);
  float* pq    = (float*)alloc((size_t)BB*UU*4);
  float* ctx   = (float*)alloc((size_t)BB*UU*4);
  float* den   = (float*)alloc((size_t)BB*4);
  float* Ex    = (float*)alloc((size_t)2016*1536*4);
  float* keys  = (float*)alloc((size_t)BB*SS*UU*4);
  unsigned short* membf = (unsigned short*)alloc((size_t)BB*SS*UU*2);
  unsigned short* embg  = (unsigned short*)alloc((size_t)2048*EMBD*2);
  unsigned short* KtT   = (unsigned short*)alloc((size_t)1536*EMBD*2);
  unsigned short* WkT   = (unsigned short*)alloc((size_t)UU*UU*2);
  unsigned short* WoT   = (unsigned short*)alloc((size_t)VV*UU*2);
  float* KbT  = (float*)alloc((size_t)1536*512*4);
  float* RTm  = (float*)alloc((size_t)1536*512*4);
  float* WqT  = (float*)alloc((size_t)512*512*4);
  float* WaT  = (float*)alloc((size_t)512*1024*4);
  unsigned short* attnall = (unsigned short*)alloc((size_t)2048*UU*2);

  init_kernel<<<512, 256, 0, stream>>>(flags, act, hnew, attnall, embg, enc);
  conv_bf16<<<(BB*SS*UU)/256, 256, 0, stream>>>(memf, membf, BB*SS*UU);
  gather_emb<<<2016, 256, 0, stream>>>(x, E, embg);
  transpose_f32<<<dim3(48,16), 256, 0, stream>>>(Kk + 256*1536, KbT, 512, 1536);
  transpose_f32<<<dim3(48,16), 256, 0, stream>>>(Rk, RTm, 512, 1536);
  transpose_f32<<<dim3(16,16), 256, 0, stream>>>(Wq, WqT, 512, 512);
  transpose_f32<<<dim3(16,32), 256, 0, stream>>>(Wa, WaT, 1024, 512);
  transpose_bf16<<<dim3(48,8), 256, 0, stream>>>(Kk, KtT, 256, 1536);
  transpose_bf16<<<dim3(16,16), 256, 0, stream>>>(Wk, WkT, 512, 512);
  transpose_bf16<<<dim3(1000,16), 256, 0, stream>>>(Wo, WoT, 512, 32000);

  gemm_bf16<<<dim3(4,32), 256, 0, stream>>>(membf, WkT, nullptr, keys, 4096, 512, 512);
  gemm_bf16<<<dim3(12,16), 256, 0, stream>>>(embg, KtT, gb, Ex, 2016, 256, 1536);

  hipFuncSetAttribute((const void*)recur_kernel,
                      hipFuncAttributeMaxDynamicSharedMemorySize, 76032);
  recur_kernel<<<NW, THR, 76032, stream>>>(Ex, keys, memf, va, gb, KbT, RTm, WqT, WaT,
                                           act, hnew, pq, ctx, den, attnall, flags);

  gemm_bf16<<<dim3(250,16), 256, 0, stream>>>(attnall, WoT, bo, out, 2016, 512, VV);
}